// Round 16
// baseline (1748.697 us; speedup 1.0000x reference)
//
#include <hip/hip_runtime.h>

#define DD 128

typedef __attribute__((ext_vector_type(8))) short bf16x8;
typedef __attribute__((ext_vector_type(4))) short bf16x4;
typedef __attribute__((ext_vector_type(4))) float f32x4;
typedef unsigned short u16;

__device__ __forceinline__ unsigned short f2bf(float f) {
  union { float f; unsigned u; } v; v.f = f;
  unsigned u = v.u;
  return (unsigned short)((u + 0x7FFFu + ((u >> 16) & 1u)) >> 16);
}
__device__ __forceinline__ float bf2f(unsigned short h) {
  union { unsigned u; float f; } v; v.u = ((unsigned)h) << 16; return v.f;
}
__device__ __forceinline__ bf16x8 pack8(f32x4 a, f32x4 b) {
  bf16x8 r;
  r[0] = (short)f2bf(a.x); r[1] = (short)f2bf(a.y);
  r[2] = (short)f2bf(a.z); r[3] = (short)f2bf(a.w);
  r[4] = (short)f2bf(b.x); r[5] = (short)f2bf(b.y);
  r[6] = (short)f2bf(b.z); r[7] = (short)f2bf(b.w);
  return r;
}

// edge_index may be int32 or int64; detect via zero high words.
__device__ __forceinline__ bool idx_is64(const int* p) {
  return (p[1] | p[3] | p[5] | p[7]) == 0;
}
__device__ __forceinline__ int ld_idx(const int* p, long long i, bool is64) {
  return is64 ? (int)((const long long*)p)[i] : p[i];
}

__global__ void k_count(const int* __restrict__ idx, int* __restrict__ cntD,
                        int* __restrict__ cntS, int E) {
  int e = blockIdx.x * blockDim.x + threadIdx.x;
  if (e >= E) return;
  bool is64 = idx_is64(idx);
  int s = ld_idx(idx, e, is64);
  int d = ld_idx(idx, (long long)E + e, is64);
  atomicAdd(&cntD[d], 1);
  atomicAdd(&cntS[s], 1);
}

// Two scans in one dispatch: block 0 scans cntD, block 1 scans cntS.
__global__ __launch_bounds__(1024) void k_scan2(
    const int* __restrict__ cntD, int* __restrict__ baseD, int* __restrict__ curD,
    const int* __restrict__ cntS, int* __restrict__ baseS, int* __restrict__ curS,
    int N) {
  const int* cnt = (blockIdx.x == 0) ? cntD : cntS;
  int* base      = (blockIdx.x == 0) ? baseD : baseS;
  int* cursor    = (blockIdx.x == 0) ? curD : curS;
  __shared__ int part[1024];
  int t = threadIdx.x;
  int chunk = (N + 1023) >> 10;
  int lo = t * chunk, hi = lo + chunk; if (hi > N) hi = N; if (lo > N) lo = N;
  int s = 0;
  for (int i = lo; i < hi; ++i) s += cnt[i];
  part[t] = s;
  __syncthreads();
  for (int off = 1; off < 1024; off <<= 1) {
    int v = (t >= off) ? part[t - off] : 0;
    __syncthreads();
    part[t] += v;
    __syncthreads();
  }
  int run = (t == 0) ? 0 : part[t - 1];
  for (int i = lo; i < hi; ++i) {
    base[i] = run; cursor[i] = run; run += cnt[i];
  }
  if (t == 1023) base[N] = part[1023];
}

// Builds src-sorted order + dst-CSR scatter positions.
__global__ void k_fill(const int* __restrict__ idx, int* __restrict__ cursorD,
                       int* __restrict__ cursorS, int* __restrict__ ss_edge,
                       int* __restrict__ ss_src, int* __restrict__ pos_csr, int E) {
  int e = blockIdx.x * blockDim.x + threadIdx.x;
  if (e >= E) return;
  bool is64 = idx_is64(idx);
  int s = ld_idx(idx, e, is64);
  int d = ld_idx(idx, (long long)E + e, is64);
  int pd = atomicAdd(&cursorD[d], 1);
  int ps = atomicAdd(&cursorS[s], 1);
  ss_edge[ps] = e;
  ss_src[ps] = s;
  pos_csr[ps] = pd;
}

// f32 -> bf16 conversion (x0 -> xb), vectorized.
__global__ void k_cvt(const float* __restrict__ in, u16* __restrict__ out, int total8) {
  int i = blockIdx.x * blockDim.x + threadIdx.x;
  if (i >= total8) return;
  f32x4 a = ((const f32x4*)in)[2 * i];
  f32x4 b = ((const f32x4*)in)[2 * i + 1];
  ((bf16x8*)out)[i] = pack8(a, b);
}

// Fused rel-GEMM + message, src-sorted order, grid-stride.
// Reads sequential/local (x bf16 always; consecutive edges share src rows);
// m scatter-written to dst-CSR rows (full 256B, non-overlapping).
// EAF32: ea source is f32 in ORIGINAL order via ss_edge (layer 0).
// BN: apply scale/shift+relu to x on load. SCAT: GEMM out f32 to orig order.
template <bool EAF32, bool BN, bool SCAT>
__global__ __launch_bounds__(256, 3) void k_gm(
    const u16* __restrict__ xbin,
    const float* __restrict__ ea0, const u16* __restrict__ eain,
    u16* __restrict__ eabout, float* __restrict__ eafout,
    u16* __restrict__ m,
    const int* __restrict__ ss_edge, const int* __restrict__ ss_src,
    const int* __restrict__ pos_csr,
    const float* __restrict__ w_rel, const float* __restrict__ b_rel,
    const float* __restrict__ scale, const float* __restrict__ shift,
    int ntE) {
  __shared__ short Wl[16384];
  for (int q = threadIdx.x; q < 4096; q += 256) {
    int off = q * 4;
    int f = off >> 7, d = off & 127;
    f32x4 w = *(const f32x4*)(w_rel + off);
    unsigned byte = ((unsigned)(f * 256 + d * 2)) ^ (unsigned)((f & 7) << 4);
    bf16x4 s4;
    s4[0] = (short)f2bf(w.x); s4[1] = (short)f2bf(w.y);
    s4[2] = (short)f2bf(w.z); s4[3] = (short)f2bf(w.w);
    *(bf16x4*)((char*)Wl + byte) = s4;
  }
  __syncthreads();
  int wave = threadIdx.x >> 6, lane = threadIdx.x & 63;
  int r = lane & 15, g = lane >> 4;
  int co = r * 8;
  float sc[8], sh[8];
  if constexpr (BN) {
    f32x4 s0 = *(const f32x4*)(scale + co), s1 = *(const f32x4*)(scale + co + 4);
    f32x4 h0 = *(const f32x4*)(shift + co), h1 = *(const f32x4*)(shift + co + 4);
#pragma unroll
    for (int j = 0; j < 4; ++j) { sc[j] = s0[j]; sc[4 + j] = s1[j]; sh[j] = h0[j]; sh[4 + j] = h1[j]; }
  }

  for (int tile = blockIdx.x * 4 + wave; tile < ntE; tile += gridDim.x * 4) {
    int k0 = tile * 16;

    // ---- GEMM A fragments (convert f32->bf16 immediately to keep regs slim) ----
    bf16x8 a8[4];
    if constexpr (EAF32) {
      int er = ss_edge[k0 + r];
      const float* rp = ea0 + (size_t)er * DD;
#pragma unroll
      for (int ks = 0; ks < 4; ++ks) {
        const float* p = rp + ks * 32 + g * 8;
        a8[ks] = pack8(*(const f32x4*)p, *(const f32x4*)(p + 4));
      }
    } else {
      const u16* rp = eain + (size_t)(k0 + r) * DD;
#pragma unroll
      for (int ks = 0; ks < 4; ++ks) a8[ks] = *(const bf16x8*)(rp + ks * 32 + g * 8);
    }

    // ---- msg-phase loads (rows g+4i, chunk r) ----
    int kk[4], sn[4], pc[4];
#pragma unroll
    for (int i = 0; i < 4; ++i) {
      kk[i] = k0 + g + 4 * i;
      sn[i] = ss_src[kk[i]];
      pc[i] = pos_csr[kk[i]];
    }
    bf16x8 xb[4], eb[4];
#pragma unroll
    for (int i = 0; i < 4; ++i) {
      xb[i] = *(const bf16x8*)(xbin + (size_t)sn[i] * DD + co);
      if constexpr (EAF32) {
        int ei = ss_edge[kk[i]];
        const float* ep = ea0 + (size_t)ei * DD + co;
        eb[i] = pack8(*(const f32x4*)ep, *(const f32x4*)(ep + 4));
      } else {
        eb[i] = *(const bf16x8*)(eain + (size_t)kk[i] * DD + co);
      }
    }

    // ---- GEMM ----
    f32x4 acc[8];
#pragma unroll
    for (int ct = 0; ct < 8; ++ct) acc[ct] = (f32x4){0.f, 0.f, 0.f, 0.f};
#pragma unroll
    for (int ct = 0; ct < 8; ++ct) {
      int f = ct * 16 + r;
      unsigned base = (unsigned)(f * 256);
      unsigned sw = (unsigned)((f & 7) << 4);
#pragma unroll
      for (int ks = 0; ks < 4; ++ks) {
        unsigned byte = (base + (unsigned)(ks * 64 + g * 16)) ^ sw;
        bf16x8 bb = *(const bf16x8*)((const char*)Wl + byte);
        acc[ct] = __builtin_amdgcn_mfma_f32_16x16x32_bf16(a8[ks], bb, acc[ct], 0, 0, 0);
      }
    }

    // ---- msg compute + scatter store ----
#pragma unroll
    for (int i = 0; i < 4; ++i) {
      bf16x8 mm;
#pragma unroll
      for (int j = 0; j < 8; ++j) {
        float xv = bf2f((u16)xb[i][j]);
        if constexpr (BN) xv = fmaxf(xv * sc[j] + sh[j], 0.f);
        mm[j] = (short)f2bf(xv * bf2f((u16)eb[i][j]));
      }
      *(bf16x8*)(m + (size_t)pc[i] * DD + co) = mm;
    }

    // ---- GEMM store ----
    size_t orow[4];
#pragma unroll
    for (int j = 0; j < 4; ++j) {
      int kr = k0 + g * 4 + j;
      orow[j] = SCAT ? (size_t)ss_edge[kr] : (size_t)kr;
    }
#pragma unroll
    for (int ct = 0; ct < 8; ++ct) {
      int col = ct * 16 + r;
      float bv = b_rel[col];
#pragma unroll
      for (int j = 0; j < 4; ++j) {
        float v = acc[ct][j] + bv;
        if constexpr (SCAT) eafout[orow[j] * DD + col] = v;
        else                eabout[orow[j] * DD + col] = f2bf(v);
      }
    }
  }
}

// Segment mean, 2 nodes per wave (independent accumulators for 2x MLP).
__global__ __launch_bounds__(256) void k_segsum(const u16* __restrict__ m,
    const int* __restrict__ row_start, u16* __restrict__ agg, int N) {
  int widx = blockIdx.x * 4 + (threadIdx.x >> 6);
  int n0 = widx * 2, n1 = n0 + 1;
  if (n0 >= N) return;
  bool has1 = n1 < N;
  int lane = threadIdx.x & 63;
  int e4 = lane >> 4, c = lane & 15, co = c * 8;
  int s0a = row_start[n0], s1a = row_start[n0 + 1];
  int len0 = s1a - s0a;
  int s0b = has1 ? row_start[n1] : 0, s1b = has1 ? row_start[n1 + 1] : 0;
  int len1 = s1b - s0b;
  int lmax = (len0 > len1) ? len0 : len1;
  float acc0[8], acc1[8];
#pragma unroll
  for (int j = 0; j < 8; ++j) { acc0[j] = 0.f; acc1[j] = 0.f; }
  for (int kk = e4; kk < lmax; kk += 4) {
    bool a0 = kk < len0, a1 = kk < len1;
    bf16x8 v0, v1;
    if (a0) v0 = *(const bf16x8*)(m + (size_t)(s0a + kk) * DD + co);
    if (a1) v1 = *(const bf16x8*)(m + (size_t)(s0b + kk) * DD + co);
    if (a0) {
#pragma unroll
      for (int j = 0; j < 8; ++j) acc0[j] += bf2f((u16)v0[j]);
    }
    if (a1) {
#pragma unroll
      for (int j = 0; j < 8; ++j) acc1[j] += bf2f((u16)v1[j]);
    }
  }
#pragma unroll
  for (int j = 0; j < 8; ++j) {
    float s = acc0[j];
    s += __shfl_xor(s, 16); s += __shfl_xor(s, 32);
    acc0[j] = s;
    float t = acc1[j];
    t += __shfl_xor(t, 16); t += __shfl_xor(t, 32);
    acc1[j] = t;
  }
  if (e4 == 0) {
    float inv = (len0 > 0) ? 1.0f / (float)len0 : 0.0f;
    f32x4 lo, hi;
#pragma unroll
    for (int j = 0; j < 4; ++j) { lo[j] = acc0[j] * inv; hi[j] = acc0[4 + j] * inv; }
    *(bf16x8*)(agg + (size_t)n0 * DD + co) = pack8(lo, hi);
  } else if (e4 == 1 && has1) {
    float inv = (len1 > 0) ? 1.0f / (float)len1 : 0.0f;
    f32x4 lo, hi;
#pragma unroll
    for (int j = 0; j < 4; ++j) { lo[j] = acc1[j] * inv; hi[j] = acc1[4 + j] * inv; }
    *(bf16x8*)(agg + (size_t)n1 * DD + co) = pack8(lo, hi);
  }
}

// Node GEMM, grid-stride: xn = agg@W_in^T + BN?(x)@W_self^T + biases.
template <bool BN, typename TO, bool STATS>
__global__ __launch_bounds__(256, 2) void k_node(const u16* __restrict__ agg,
    const u16* __restrict__ xc, const float* __restrict__ W_in,
    const float* __restrict__ W_self, const float* __restrict__ b_in,
    const float* __restrict__ b_self, const int* __restrict__ row_start,
    const float* __restrict__ scale, const float* __restrict__ shift,
    TO* __restrict__ xn, float* __restrict__ gsum, float* __restrict__ gssq,
    int ntiles) {
  __shared__ short Wl[DD * 256];
  for (int q = threadIdx.x; q < DD * 256 / 4; q += 256) {
    int off = q * 4;
    int f = off >> 8, k = off & 255;
    f32x4 w = (k < 128) ? *(const f32x4*)(W_in + f * 128 + k)
                        : *(const f32x4*)(W_self + f * 128 + (k - 128));
    unsigned byte = ((unsigned)(f * 512 + k * 2)) ^ (unsigned)((f & 7) << 4);
    bf16x4 s4;
    s4[0] = (short)f2bf(w.x); s4[1] = (short)f2bf(w.y);
    s4[2] = (short)f2bf(w.z); s4[3] = (short)f2bf(w.w);
    *(bf16x4*)((char*)Wl + byte) = s4;
  }
  __syncthreads();
  int wave = threadIdx.x >> 6, lane = threadIdx.x & 63;
  int r = lane & 15, g = lane >> 4;
  for (int tile = blockIdx.x * 4 + wave; tile < ntiles; tile += gridDim.x * 4) {
    int arowi = tile * 16 + r;
    const u16* arow = agg + (size_t)arowi * DD;
    const u16* xrow = xc + (size_t)arowi * DD;
    bf16x8 a[8];
#pragma unroll
    for (int ks = 0; ks < 4; ++ks) a[ks] = *(const bf16x8*)(arow + ks * 32 + g * 8);
#pragma unroll
    for (int ks = 0; ks < 4; ++ks) {
      int c0 = ks * 32 + g * 8;
      bf16x8 raw = *(const bf16x8*)(xrow + c0);
      if constexpr (BN) {
        bf16x8 fr;
#pragma unroll
        for (int j = 0; j < 8; ++j) {
          float f = fmaxf(bf2f((u16)raw[j]) * scale[c0 + j] + shift[c0 + j], 0.f);
          fr[j] = (short)f2bf(f);
        }
        a[4 + ks] = fr;
      } else {
        a[4 + ks] = raw;
      }
    }
    f32x4 acc[8];
#pragma unroll
    for (int ct = 0; ct < 8; ++ct) acc[ct] = (f32x4){0.f, 0.f, 0.f, 0.f};
#pragma unroll
    for (int ct = 0; ct < 8; ++ct) {
      int f = ct * 16 + r;
      unsigned base = (unsigned)(f * 512);
      unsigned sw = (unsigned)((f & 7) << 4);
#pragma unroll
      for (int ks = 0; ks < 8; ++ks) {
        unsigned byte = (base + (unsigned)(ks * 64 + g * 16)) ^ sw;
        bf16x8 b = *(const bf16x8*)((const char*)Wl + byte);
        acc[ct] = __builtin_amdgcn_mfma_f32_16x16x32_bf16(a[ks], b, acc[ct], 0, 0, 0);
      }
    }
    int nbase = tile * 16;
    float degmask[4];
#pragma unroll
    for (int j = 0; j < 4; ++j) {
      int nn = nbase + g * 4 + j;
      degmask[j] = (row_start[nn + 1] > row_start[nn]) ? 1.0f : 0.0f;
    }
#pragma unroll
    for (int ct = 0; ct < 8; ++ct) {
      int col = ct * 16 + r;
      float bi = b_in[col], bs = b_self[col];
      float s = 0.f, s2 = 0.f;
#pragma unroll
      for (int j = 0; j < 4; ++j) {
        float v = acc[ct][j] + bs + bi * degmask[j];
        if constexpr (sizeof(TO) == 2) xn[(size_t)(nbase + g * 4 + j) * DD + col] = (TO)f2bf(v);
        else                            xn[(size_t)(nbase + g * 4 + j) * DD + col] = (TO)v;
        s += v; s2 += v * v;
      }
      if constexpr (STATS) {
        s += __shfl_xor(s, 16);  s += __shfl_xor(s, 32);
        s2 += __shfl_xor(s2, 16); s2 += __shfl_xor(s2, 32);
        if (g == 0) { atomicAdd(&gsum[col], s); atomicAdd(&gssq[col], s2); }
      }
    }
  }
}

__global__ void k_bnfin(float* __restrict__ gsum, float* __restrict__ gssq,
    const float* __restrict__ gamma, const float* __restrict__ beta,
    float* __restrict__ scale, float* __restrict__ shift, int N) {
  int d = threadIdx.x;
  float mu = gsum[d] / (float)N;
  float var = gssq[d] / (float)N - mu * mu;
  float rs = rsqrtf(var + 1e-5f);
  float sc = rs * gamma[d];
  scale[d] = sc;
  shift[d] = beta[d] - mu * sc;
  gsum[d] = 0.f;
  gssq[d] = 0.f;
}

static inline size_t alignup(size_t v, size_t a) { return (v + a - 1) & ~(a - 1); }

extern "C" void kernel_launch(void* const* d_in, const int* in_sizes, int n_in,
                              void* d_out, int out_size, void* d_ws, size_t ws_size,
                              hipStream_t stream) {
  const float* x0     = (const float*)d_in[0];
  const float* ea0    = (const float*)d_in[1];
  const float* w_self = (const float*)d_in[2];
  const float* b_self = (const float*)d_in[3];
  const float* w_in   = (const float*)d_in[4];
  const float* b_in   = (const float*)d_in[5];
  const float* w_rel  = (const float*)d_in[6];
  const float* b_rel  = (const float*)d_in[7];
  const float* gamma  = (const float*)d_in[8];
  const float* beta   = (const float*)d_in[9];
  const int*   idx    = (const int*)d_in[10];

  const int N = in_sizes[0] / DD;
  const int E = in_sizes[1] / DD;

  char* w = (char*)d_ws;
  size_t off = 0;
  int* cntD      = (int*)(w + off); off = alignup(off + (size_t)N * 4, 256);
  int* cntS      = (int*)(w + off); off = alignup(off + (size_t)N * 4, 256);
  int* row_start = (int*)(w + off); off = alignup(off + (size_t)(N + 1) * 4, 256);
  int* col_start = (int*)(w + off); off = alignup(off + (size_t)(N + 1) * 4, 256);
  int* cursorD   = (int*)(w + off); off = alignup(off + (size_t)N * 4, 256);
  int* cursorS   = (int*)(w + off); off = alignup(off + (size_t)N * 4, 256);
  int* ss_edge   = (int*)(w + off); off = alignup(off + (size_t)E * 4, 256);
  int* ss_src    = (int*)(w + off); off = alignup(off + (size_t)E * 4, 256);
  int* pos_csr   = (int*)(w + off); off = alignup(off + (size_t)E * 4, 256);
  float* gstats  = (float*)(w + off); off = alignup(off + 256 * 4, 256);
  float* scale   = (float*)(w + off); off = alignup(off + 128 * 4, 256);
  float* shift   = (float*)(w + off); off = alignup(off + 128 * 4, 256);
  u16* agg       = (u16*)(w + off); off = alignup(off + (size_t)N * DD * 2, 256);
  u16* xbA       = (u16*)(w + off); off = alignup(off + (size_t)N * DD * 2, 256);
  u16* xbB       = (u16*)(w + off); off = alignup(off + (size_t)N * DD * 2, 256);
  u16* eaA       = (u16*)(w + off); off = alignup(off + (size_t)E * DD * 2, 256);
  u16* eaB       = (u16*)(w + off); off = alignup(off + (size_t)E * DD * 2, 256);
  u16* mbuf      = (u16*)(w + off); off = alignup(off + (size_t)E * DD * 2, 256);
  float* gsum = gstats, *gssq = gstats + 128;
  (void)ws_size; (void)n_in; (void)out_size;

  float* out_x  = (float*)d_out;
  float* out_ea = out_x + (size_t)N * DD;

  // ---- dual-order CSR build + x0 conversion ----
  (void)hipMemsetAsync(cntD, 0, (size_t)N * 4, stream);
  (void)hipMemsetAsync(cntS, 0, (size_t)N * 4, stream);
  int ethreads = 256, eblocks = (E + ethreads - 1) / ethreads;
  k_count<<<eblocks, ethreads, 0, stream>>>(idx, cntD, cntS, E);
  k_scan2<<<2, 1024, 0, stream>>>(cntD, row_start, cursorD,
                                  cntS, col_start, cursorS, N);
  k_fill<<<eblocks, ethreads, 0, stream>>>(idx, cursorD, cursorS,
      ss_edge, ss_src, pos_csr, E);
  k_cvt<<<((size_t)N * DD / 8 + 255) / 256, 256, 0, stream>>>(x0, xbA, N * DD / 8);
  (void)hipMemsetAsync(gstats, 0, 256 * 4, stream);

  const int ntN = N / 16;
  const int ntE = E / 16;
  const int gmBlocks = 1024;
  const int segBlocks = (N / 2 + 3) / 4;   // 2 nodes per wave
  const int nodeBlocks = 384;

  // ---- layer 0 ----
  k_gm<true, false, false><<<gmBlocks, 256, 0, stream>>>(xbA, ea0, nullptr,
      eaA, nullptr, mbuf, ss_edge, ss_src, pos_csr,
      w_rel, b_rel, scale, shift, ntE);
  k_segsum<<<segBlocks, 256, 0, stream>>>(mbuf, row_start, agg, N);
  k_node<false, u16, true><<<nodeBlocks, 256, 0, stream>>>(agg, xbA,
      w_in, w_self, b_in, b_self, row_start, scale, shift, xbB, gsum, gssq, ntN);
  k_bnfin<<<1, 128, 0, stream>>>(gsum, gssq, gamma, beta, scale, shift, N);

  // ---- layer 1 ----
  k_gm<false, true, false><<<gmBlocks, 256, 0, stream>>>(xbB, nullptr, eaA,
      eaB, nullptr, mbuf, ss_edge, ss_src, pos_csr,
      w_rel + DD * DD, b_rel + DD, scale, shift, ntE);
  k_segsum<<<segBlocks, 256, 0, stream>>>(mbuf, row_start, agg, N);
  k_node<true, u16, true><<<nodeBlocks, 256, 0, stream>>>(agg, xbB,
      w_in + DD * DD, w_self + DD * DD, b_in + DD, b_self + DD,
      row_start, scale, shift, xbA, gsum, gssq, ntN);
  k_bnfin<<<1, 128, 0, stream>>>(gsum, gssq, gamma + DD, beta + DD, scale, shift, N);

  // ---- layer 2 ----
  k_gm<false, true, true><<<gmBlocks, 256, 0, stream>>>(xbA, nullptr, eaB,
      nullptr, out_ea, mbuf, ss_edge, ss_src, pos_csr,
      w_rel + 2 * DD * DD, b_rel + 2 * DD, scale, shift, ntE);
  k_segsum<<<segBlocks, 256, 0, stream>>>(mbuf, row_start, agg, N);
  k_node<true, float, false><<<nodeBlocks, 256, 0, stream>>>(agg, xbA,
      w_in + 2 * DD * DD, w_self + 2 * DD * DD, b_in + 2 * DD, b_self + 2 * DD,
      row_start, scale, shift, out_x, gsum, gssq, ntN);
}

// Round 17
// 1011.331 us; speedup vs baseline: 1.7291x; 1.7291x over previous
//
#include <hip/hip_runtime.h>

#define DD 128

typedef __attribute__((ext_vector_type(8))) short bf16x8;
typedef __attribute__((ext_vector_type(4))) short bf16x4;
typedef __attribute__((ext_vector_type(4))) float f32x4;
typedef unsigned short u16;

__device__ __forceinline__ unsigned short f2bf(float f) {
  union { float f; unsigned u; } v; v.f = f;
  unsigned u = v.u;
  return (unsigned short)((u + 0x7FFFu + ((u >> 16) & 1u)) >> 16);
}
__device__ __forceinline__ float bf2f(unsigned short h) {
  union { unsigned u; float f; } v; v.u = ((unsigned)h) << 16; return v.f;
}
__device__ __forceinline__ bf16x8 pack8(f32x4 a, f32x4 b) {
  bf16x8 r;
  r[0] = (short)f2bf(a.x); r[1] = (short)f2bf(a.y);
  r[2] = (short)f2bf(a.z); r[3] = (short)f2bf(a.w);
  r[4] = (short)f2bf(b.x); r[5] = (short)f2bf(b.y);
  r[6] = (short)f2bf(b.z); r[7] = (short)f2bf(b.w);
  return r;
}

// edge_index may be int32 or int64; detect via zero high words.
__device__ __forceinline__ bool idx_is64(const int* p) {
  return (p[1] | p[3] | p[5] | p[7]) == 0;
}
__device__ __forceinline__ int ld_idx(const int* p, long long i, bool is64) {
  return is64 ? (int)((const long long*)p)[i] : p[i];
}

__global__ void k_count(const int* __restrict__ idx, int* __restrict__ cnt, int E) {
  int e = blockIdx.x * blockDim.x + threadIdx.x;
  if (e >= E) return;
  bool is64 = idx_is64(idx);
  int d = ld_idx(idx, (long long)E + e, is64);
  atomicAdd(&cnt[d], 1);
}

__global__ __launch_bounds__(1024) void k_scan(const int* __restrict__ cnt,
    int* __restrict__ row_start, int* __restrict__ cursor, int N) {
  __shared__ int part[1024];
  int t = threadIdx.x;
  int chunk = (N + 1023) >> 10;
  int lo = t * chunk, hi = lo + chunk; if (hi > N) hi = N; if (lo > N) lo = N;
  int s = 0;
  for (int i = lo; i < hi; ++i) s += cnt[i];
  part[t] = s;
  __syncthreads();
  for (int off = 1; off < 1024; off <<= 1) {
    int v = (t >= off) ? part[t - off] : 0;
    __syncthreads();
    part[t] += v;
    __syncthreads();
  }
  int run = (t == 0) ? 0 : part[t - 1];
  for (int i = lo; i < hi; ++i) {
    row_start[i] = run; cursor[i] = run; run += cnt[i];
  }
  if (t == 1023) row_start[N] = part[1023];
}

__global__ void k_fill(const int* __restrict__ idx, int* __restrict__ cursor,
                       int* __restrict__ edge_of, int* __restrict__ src_csr, int E) {
  int e = blockIdx.x * blockDim.x + threadIdx.x;
  if (e >= E) return;
  bool is64 = idx_is64(idx);
  int s = ld_idx(idx, e, is64);
  int d = ld_idx(idx, (long long)E + e, is64);
  int pos = atomicAdd(&cursor[d], 1);
  edge_of[pos] = e;
  src_csr[pos] = s;
}

// Fused agg + rel, one dispatch per layer (R12 configuration — best measured).
//  A-blocks (bid < nA): wave per node, segment-mean -> aggm (bf16).
//    16 edges in flight per iteration (esub covers 4, kk-unroll x4).
//  B-blocks: rel GEMM with 32KB swizzled weight LDS, wave per 16-edge tile.
template <int MODE>
__global__ __launch_bounds__(256, 4) void k_ar(
    const float* __restrict__ x0, const u16* __restrict__ xbin,
    const float* __restrict__ ea0, const u16* __restrict__ eain,
    u16* __restrict__ eabout, float* __restrict__ eafout,
    float* __restrict__ aggmf, u16* __restrict__ aggm,
    const int* __restrict__ row_start, const int* __restrict__ edge_of,
    const int* __restrict__ src_csr,
    const float* __restrict__ w_rel, const float* __restrict__ b_rel,
    const float* __restrict__ scale, const float* __restrict__ shift,
    int nA, int ntE) {
  __shared__ short Wl[16384];    // 32 KB (B-blocks only)
  int bid = blockIdx.x;
  int tid = threadIdx.x;
  int wave = tid >> 6, lane = tid & 63;
  (void)aggmf;

  if (bid < nA) {
    // ---------------- A: aggregation ----------------
    int n = bid * 4 + wave;
    int esub = lane >> 4, cg = lane & 15;
    int c0 = cg * 8;
    float scA[8], shA[8];
    if constexpr (MODE >= 1) {
#pragma unroll
      for (int j = 0; j < 8; ++j) { scA[j] = scale[c0 + j]; shA[j] = shift[c0 + j]; }
    }
    int s0 = row_start[n], s1 = row_start[n + 1];
    int len = s1 - s0;
    float acc[8];
#pragma unroll
    for (int j = 0; j < 8; ++j) acc[j] = 0.f;
    for (int kk = 0; kk < len; kk += 16) {
      int kx[4];
      bool av[4];
      int kq[4];
#pragma unroll
      for (int u = 0; u < 4; ++u) {
        kx[u] = kk + 4 * u + esub;
        av[u] = kx[u] < len;
        kq[u] = s0 + (av[u] ? kx[u] : 0);
      }
      if constexpr (MODE == 0) {
        int eo[4], sn[4];
#pragma unroll
        for (int u = 0; u < 4; ++u) { eo[u] = edge_of[kq[u]]; sn[u] = src_csr[kq[u]]; }
        f32x4 ea_a[4], ea_b[4], xv_a[4], xv_b[4];
#pragma unroll
        for (int u = 0; u < 4; ++u) {
          const float* ep = ea0 + (size_t)eo[u] * DD + c0;
          const float* xp = x0 + (size_t)sn[u] * DD + c0;
          ea_a[u] = *(const f32x4*)ep; ea_b[u] = *(const f32x4*)(ep + 4);
          xv_a[u] = *(const f32x4*)xp; xv_b[u] = *(const f32x4*)(xp + 4);
        }
#pragma unroll
        for (int u = 0; u < 4; ++u) {
          if (av[u]) {
#pragma unroll
            for (int j = 0; j < 4; ++j) {
              acc[j] += xv_a[u][j] * ea_a[u][j];
              acc[4 + j] += xv_b[u][j] * ea_b[u][j];
            }
          }
        }
      } else {
        int sn[4];
#pragma unroll
        for (int u = 0; u < 4; ++u) sn[u] = src_csr[kq[u]];
        bf16x8 ev[4], xv[4];
#pragma unroll
        for (int u = 0; u < 4; ++u) {
          ev[u] = *(const bf16x8*)(eain + (size_t)kq[u] * DD + c0);
          xv[u] = *(const bf16x8*)(xbin + (size_t)sn[u] * DD + c0);
        }
#pragma unroll
        for (int u = 0; u < 4; ++u) {
          if (av[u]) {
#pragma unroll
            for (int j = 0; j < 8; ++j) {
              float xf = fmaxf(bf2f((u16)xv[u][j]) * scA[j] + shA[j], 0.f);
              acc[j] += xf * bf2f((u16)ev[u][j]);
            }
          }
        }
      }
    }
    float invd = (len > 0) ? 1.0f / (float)len : 0.0f;
#pragma unroll
    for (int j = 0; j < 8; ++j) {
      float s = acc[j];
      s += __shfl_xor(s, 16);
      s += __shfl_xor(s, 32);
      acc[j] = s * invd;
    }
    if (esub == 0) {
      f32x4 lo, hi;
#pragma unroll
      for (int j = 0; j < 4; ++j) { lo[j] = acc[j]; hi[j] = acc[4 + j]; }
      *(bf16x8*)(aggm + (size_t)n * DD + c0) = pack8(lo, hi);
    }
  } else {
    // ---------------- B: rel GEMM ----------------
    for (int q = tid; q < 4096; q += 256) {
      int off = q * 4;
      int f = off >> 7, d = off & 127;
      f32x4 w = *(const f32x4*)(w_rel + off);
      unsigned byte = ((unsigned)(f * 256 + d * 2)) ^ (unsigned)((f & 7) << 4);
      bf16x4 s4;
      s4[0] = (short)f2bf(w.x); s4[1] = (short)f2bf(w.y);
      s4[2] = (short)f2bf(w.z); s4[3] = (short)f2bf(w.w);
      *(bf16x4*)((char*)Wl + byte) = s4;
    }
    __syncthreads();
    int r = lane & 15, g = lane >> 4;
    int tile = (bid - nA) * 4 + wave;
    if (tile >= ntE) return;
    bf16x8 a8[4];
    if constexpr (MODE == 0) {
      int er = edge_of[tile * 16 + r];
      const float* rp = ea0 + (size_t)er * DD;
#pragma unroll
      for (int ks = 0; ks < 4; ++ks) {
        const float* p = rp + ks * 32 + g * 8;
        a8[ks] = pack8(*(const f32x4*)p, *(const f32x4*)(p + 4));
      }
    } else {
      const u16* rp = eain + (size_t)(tile * 16 + r) * DD;
#pragma unroll
      for (int ks = 0; ks < 4; ++ks) a8[ks] = *(const bf16x8*)(rp + ks * 32 + g * 8);
    }
    f32x4 acc4[8];
#pragma unroll
    for (int ct = 0; ct < 8; ++ct) acc4[ct] = (f32x4){0.f, 0.f, 0.f, 0.f};
#pragma unroll
    for (int ct = 0; ct < 8; ++ct) {
      int f = ct * 16 + r;
      unsigned base = (unsigned)(f * 256);
      unsigned sw = (unsigned)((f & 7) << 4);
#pragma unroll
      for (int ks = 0; ks < 4; ++ks) {
        unsigned byte = (base + (unsigned)(ks * 64 + g * 16)) ^ sw;
        bf16x8 bb = *(const bf16x8*)((const char*)Wl + byte);
        acc4[ct] = __builtin_amdgcn_mfma_f32_16x16x32_bf16(a8[ks], bb, acc4[ct], 0, 0, 0);
      }
    }
    size_t orow[4];
#pragma unroll
    for (int j = 0; j < 4; ++j) {
      int kr = tile * 16 + g * 4 + j;
      if constexpr (MODE == 2) orow[j] = (size_t)edge_of[kr];
      else                     orow[j] = (size_t)kr;
    }
#pragma unroll
    for (int ct = 0; ct < 8; ++ct) {
      int col = ct * 16 + r;
      float bv = b_rel[col];
#pragma unroll
      for (int j = 0; j < 4; ++j) {
        float v = acc4[ct][j] + bv;
        if constexpr (MODE == 2) eafout[orow[j] * DD + col] = v;
        else                     eabout[orow[j] * DD + col] = f2bf(v);
      }
    }
  }
}

// Node GEMM: xn = aggm @ W_in^T + BN?(x) @ W_self^T + b_self + (deg>0)*b_in.
template <typename TX, bool BN, typename TO, bool STATS>
__global__ __launch_bounds__(256, 2) void k_node(const u16* __restrict__ aggm,
    const TX* __restrict__ xc, const float* __restrict__ W_in,
    const float* __restrict__ W_self, const float* __restrict__ b_in,
    const float* __restrict__ b_self, const int* __restrict__ row_start,
    const float* __restrict__ scale, const float* __restrict__ shift,
    TO* __restrict__ xn, float* __restrict__ gsum, float* __restrict__ gssq,
    int ntiles) {
  __shared__ short Wl[DD * 256];
  for (int q = threadIdx.x; q < DD * 256 / 4; q += 256) {
    int off = q * 4;
    int f = off >> 8, k = off & 255;
    f32x4 w = (k < 128) ? *(const f32x4*)(W_in + f * 128 + k)
                        : *(const f32x4*)(W_self + f * 128 + (k - 128));
    unsigned byte = ((unsigned)(f * 512 + k * 2)) ^ (unsigned)((f & 7) << 4);
    bf16x4 s4;
    s4[0] = (short)f2bf(w.x); s4[1] = (short)f2bf(w.y);
    s4[2] = (short)f2bf(w.z); s4[3] = (short)f2bf(w.w);
    *(bf16x4*)((char*)Wl + byte) = s4;
  }
  __syncthreads();
  int wave = threadIdx.x >> 6, lane = threadIdx.x & 63;
  int tile = blockIdx.x * 4 + wave;
  if (tile >= ntiles) return;
  int r = lane & 15, g = lane >> 4;
  int arowi = tile * 16 + r;
  const u16* arow = aggm + (size_t)arowi * DD;
  const TX* xrow = xc + (size_t)arowi * DD;
  bf16x8 a[8];
#pragma unroll
  for (int ks = 0; ks < 4; ++ks) a[ks] = *(const bf16x8*)(arow + ks * 32 + g * 8);
#pragma unroll
  for (int ks = 0; ks < 4; ++ks) {
    int c0 = ks * 32 + g * 8;
    if constexpr (sizeof(TX) == 2) {
      bf16x8 raw = *(const bf16x8*)(xrow + c0);
      if constexpr (BN) {
        bf16x8 fr;
#pragma unroll
        for (int j = 0; j < 8; ++j) {
          float f = fmaxf(bf2f((u16)raw[j]) * scale[c0 + j] + shift[c0 + j], 0.f);
          fr[j] = (short)f2bf(f);
        }
        a[4 + ks] = fr;
      } else {
        a[4 + ks] = raw;
      }
    } else {
      const float* p = (const float*)xrow + c0;
      a[4 + ks] = pack8(*(const f32x4*)p, *(const f32x4*)(p + 4));
    }
  }
  f32x4 acc[8];
#pragma unroll
  for (int ct = 0; ct < 8; ++ct) acc[ct] = (f32x4){0.f, 0.f, 0.f, 0.f};
#pragma unroll
  for (int ct = 0; ct < 8; ++ct) {
    int f = ct * 16 + r;
    unsigned base = (unsigned)(f * 512);
    unsigned sw = (unsigned)((f & 7) << 4);
#pragma unroll
    for (int ks = 0; ks < 8; ++ks) {
      unsigned byte = (base + (unsigned)(ks * 64 + g * 16)) ^ sw;
      bf16x8 b = *(const bf16x8*)((const char*)Wl + byte);
      acc[ct] = __builtin_amdgcn_mfma_f32_16x16x32_bf16(a[ks], b, acc[ct], 0, 0, 0);
    }
  }
  int nbase = tile * 16;
  float degmask[4];
#pragma unroll
  for (int j = 0; j < 4; ++j) {
    int nn = nbase + g * 4 + j;
    degmask[j] = (row_start[nn + 1] > row_start[nn]) ? 1.0f : 0.0f;
  }
#pragma unroll
  for (int ct = 0; ct < 8; ++ct) {
    int col = ct * 16 + r;
    float bi = b_in[col], bs = b_self[col];
    float s = 0.f, s2 = 0.f;
#pragma unroll
    for (int j = 0; j < 4; ++j) {
      float v = acc[ct][j] + bs + bi * degmask[j];
      if constexpr (sizeof(TO) == 2) xn[(size_t)(nbase + g * 4 + j) * DD + col] = (TO)f2bf(v);
      else                            xn[(size_t)(nbase + g * 4 + j) * DD + col] = (TO)v;
      s += v; s2 += v * v;
    }
    if constexpr (STATS) {
      s += __shfl_xor(s, 16);  s += __shfl_xor(s, 32);
      s2 += __shfl_xor(s2, 16); s2 += __shfl_xor(s2, 32);
      if (g == 0) { atomicAdd(&gsum[col], s); atomicAdd(&gssq[col], s2); }
    }
  }
}

// Finalize BN scale/shift; zero stats for the next layer.
__global__ void k_bnfin(float* __restrict__ gsum, float* __restrict__ gssq,
    const float* __restrict__ gamma, const float* __restrict__ beta,
    float* __restrict__ scale, float* __restrict__ shift, int N) {
  int d = threadIdx.x;
  float mu = gsum[d] / (float)N;
  float var = gssq[d] / (float)N - mu * mu;
  float rs = rsqrtf(var + 1e-5f);
  float sc = rs * gamma[d];
  scale[d] = sc;
  shift[d] = beta[d] - mu * sc;
  gsum[d] = 0.f;
  gssq[d] = 0.f;
}

static inline size_t alignup(size_t v, size_t a) { return (v + a - 1) & ~(a - 1); }

extern "C" void kernel_launch(void* const* d_in, const int* in_sizes, int n_in,
                              void* d_out, int out_size, void* d_ws, size_t ws_size,
                              hipStream_t stream) {
  const float* x0     = (const float*)d_in[0];
  const float* ea0    = (const float*)d_in[1];
  const float* w_self = (const float*)d_in[2];
  const float* b_self = (const float*)d_in[3];
  const float* w_in   = (const float*)d_in[4];
  const float* b_in   = (const float*)d_in[5];
  const float* w_rel  = (const float*)d_in[6];
  const float* b_rel  = (const float*)d_in[7];
  const float* gamma  = (const float*)d_in[8];
  const float* beta   = (const float*)d_in[9];
  const int*   idx    = (const int*)d_in[10];

  const int N = in_sizes[0] / DD;
  const int E = in_sizes[1] / DD;

  char* w = (char*)d_ws;
  size_t off = 0;
  int* cnt       = (int*)(w + off); off = alignup(off + (size_t)N * 4, 256);
  int* row_start = (int*)(w + off); off = alignup(off + (size_t)(N + 1) * 4, 256);
  int* cursor    = (int*)(w + off); off = alignup(off + (size_t)N * 4, 256);
  int* edge_of   = (int*)(w + off); off = alignup(off + (size_t)E * 4, 256);
  int* src_csr   = (int*)(w + off); off = alignup(off + (size_t)E * 4, 256);
  float* gstats  = (float*)(w + off); off = alignup(off + 256 * 4, 256);
  float* scale   = (float*)(w + off); off = alignup(off + 128 * 4, 256);
  float* shift   = (float*)(w + off); off = alignup(off + 128 * 4, 256);
  u16* aggm      = (u16*)(w + off); off = alignup(off + (size_t)N * DD * 2, 256);
  u16* xbA       = (u16*)(w + off); off = alignup(off + (size_t)N * DD * 2, 256);
  u16* xbB       = (u16*)(w + off); off = alignup(off + (size_t)N * DD * 2, 256);
  u16* eaA       = (u16*)(w + off); off = alignup(off + (size_t)E * DD * 2, 256);
  u16* eaB       = (u16*)(w + off); off = alignup(off + (size_t)E * DD * 2, 256);
  float* gsum = gstats, *gssq = gstats + 128;
  (void)ws_size; (void)n_in; (void)out_size;

  float* out_x  = (float*)d_out;
  float* out_ea = out_x + (size_t)N * DD;

  // ---- CSR build ----
  (void)hipMemsetAsync(cnt, 0, (size_t)N * 4, stream);
  int ethreads = 256, eblocks = (E + ethreads - 1) / ethreads;
  k_count<<<eblocks, ethreads, 0, stream>>>(idx, cnt, E);
  k_scan<<<1, 1024, 0, stream>>>(cnt, row_start, cursor, N);
  k_fill<<<eblocks, ethreads, 0, stream>>>(idx, cursor, edge_of, src_csr, E);
  (void)hipMemsetAsync(gstats, 0, 256 * 4, stream);

  const int ntN = N / 16;                 // 3125
  const int ntE = E / 16;                 // 40000
  const int nA = (N + 3) / 4;             // 12500 A-blocks (wave per node)
  const int nB = (ntE + 3) / 4;           // 10000 B-blocks (wave per tile)
  const int grid = nA + nB;
  const int nodeBlocks = (ntN + 3) / 4;

  // ---- layer 0 ----
  k_ar<0><<<grid, 256, 0, stream>>>(x0, nullptr, ea0, nullptr,
      eaA, nullptr, nullptr, aggm, row_start, edge_of, src_csr,
      w_rel, b_rel, scale, shift, nA, ntE);
  k_node<float, false, u16, true><<<nodeBlocks, 256, 0, stream>>>(aggm, x0,
      w_in, w_self, b_in, b_self, row_start, scale, shift,
      xbA, gsum, gssq, ntN);
  k_bnfin<<<1, 128, 0, stream>>>(gsum, gssq, gamma, beta, scale, shift, N);

  // ---- layer 1 ----
  k_ar<1><<<grid, 256, 0, stream>>>(nullptr, xbA, nullptr, eaA,
      eaB, nullptr, nullptr, aggm, row_start, edge_of, src_csr,
      w_rel + DD * DD, b_rel + DD, scale, shift, nA, ntE);
  k_node<u16, true, u16, true><<<nodeBlocks, 256, 0, stream>>>(aggm, xbA,
      w_in + DD * DD, w_self + DD * DD, b_in + DD, b_self + DD,
      row_start, scale, shift, xbB, gsum, gssq, ntN);
  k_bnfin<<<1, 128, 0, stream>>>(gsum, gssq, gamma + DD, beta + DD, scale, shift, N);

  // ---- layer 2 ----
  k_ar<2><<<grid, 256, 0, stream>>>(nullptr, xbB, nullptr, eaB,
      nullptr, out_ea, nullptr, aggm, row_start, edge_of, src_csr,
      w_rel + 2 * DD * DD, b_rel + 2 * DD, scale, shift, nA, ntE);
  k_node<u16, true, float, false><<<nodeBlocks, 256, 0, stream>>>(aggm, xbB,
      w_in + 2 * DD * DD, w_self + 2 * DD * DD, b_in + 2 * DD, b_self + 2 * DD,
      row_start, scale, shift, out_x, gsum, gssq, ntN);
}